// Round 3
// baseline (404.130 us; speedup 1.0000x reference)
//
#include <hip/hip_runtime.h>
#include <hip/hip_bf16.h>

#define SEQ 1024
#define NH 8
#define HD 64
#define HID 512
#define BATCH 32

typedef _Float16 f16;
typedef f16 f16x4 __attribute__((ext_vector_type(4)));
typedef f16 f16x8 __attribute__((ext_vector_type(8)));
typedef float f32x4 __attribute__((ext_vector_type(4)));

// ---------------------------------------------------------------------------
// Kernel 1: transpose weights to f16, k-contiguous (B-operand layout)
// ---------------------------------------------------------------------------
__global__ __launch_bounds__(256) void transpose_w(const float* __restrict__ wq,
                                                   const float* __restrict__ wp,
                                                   f16* __restrict__ wTq,
                                                   f16* __restrict__ wTp) {
    int flat = blockIdx.x * 256 + threadIdx.x;
    if (flat < 64 * 1536) {
        int e = flat / 1536, j = flat % 1536;
        wTq[(size_t)j * 64 + e] = (f16)wq[flat];
    } else {
        int f2 = flat - 64 * 1536;
        int k = f2 / 64, n = f2 % 64;
        wTp[(size_t)n * 512 + k] = (f16)wp[f2];
    }
}

// ---------------------------------------------------------------------------
// Kernel 2: QKV projection. 64 rows x one head per block. MFMA + LDS-bounce
// epilogue with coalesced b128 stores.
//   Qb[bh][n][d], Kb[bh][n][d], Vtb[bh][d][n]
// ---------------------------------------------------------------------------
__global__ __launch_bounds__(256) void qkv_kernel(const float* __restrict__ x,
                                                  const f16* __restrict__ wTq,
                                                  const float* __restrict__ b_qkv,
                                                  f16* __restrict__ Qb,
                                                  f16* __restrict__ Kb,
                                                  f16* __restrict__ Vtb) {
    __shared__ __align__(16) char smem[36864];
    f16* xs = (f16*)smem;                  // [64][72]
    f16* wsh = (f16*)(smem + 9216);        // [192][72]
    f16* outs = (f16*)smem;                // [3][64][72]

    const int n0   = blockIdx.x * 64;
    const int bh   = blockIdx.y;
    const int b    = bh >> 3, h = bh & 7;
    const int tid  = threadIdx.x;
    const int wave = tid >> 6, lane = tid & 63;
    const int quad = lane >> 4, l16 = lane & 15;

    for (int p = 0; p < 2; p++) {
        int t = tid + p * 256;
        int row = t >> 3, col = (t & 7) * 8;
        const float* src = x + ((size_t)(b * SEQ + n0 + row)) * 64 + col;
        float4 a0 = *(const float4*)src;
        float4 a1 = *(const float4*)(src + 4);
        f16x8 v = {(f16)a0.x, (f16)a0.y, (f16)a0.z, (f16)a0.w,
                   (f16)a1.x, (f16)a1.y, (f16)a1.z, (f16)a1.w};
        *(f16x8*)(&xs[row * 72 + col]) = v;
    }
    for (int p = 0; p < 6; p++) {
        int row = p * 32 + (tid >> 3), col = (tid & 7) * 8;
        *(f16x8*)(&wsh[row * 72 + col]) =
            *(const f16x8*)(wTq + (size_t)(h * 192 + row) * 64 + col);
    }
    __syncthreads();

    f16x8 af[2];
    af[0] = *(const f16x8*)(&xs[(wave * 16 + l16) * 72 + quad * 8]);
    af[1] = *(const f16x8*)(&xs[(wave * 16 + l16) * 72 + quad * 8 + 32]);

    f32x4 acc[12];
    f32x4 z = {0.f, 0.f, 0.f, 0.f};
    for (int jt = 0; jt < 12; jt++) acc[jt] = z;
    for (int jt = 0; jt < 12; jt++)
        for (int ss = 0; ss < 2; ss++) {
            f16x8 bf = *(const f16x8*)(&wsh[(jt * 16 + l16) * 72 + quad * 8 + ss * 32]);
            acc[jt] = __builtin_amdgcn_mfma_f32_16x16x32_f16(af[ss], bf, acc[jt], 0, 0, 0);
        }

    __syncthreads();   // done reading xs/wsh; reuse as outs

    for (int jt = 0; jt < 12; jt++) {
        int jl = jt * 16 + l16;
        float bias = b_qkv[h * 192 + jl];
        int d = jl / 3, c = jl - 3 * d;
        for (int r = 0; r < 4; r++) {
            int nl = wave * 16 + quad * 4 + r;
            int off = (c < 2) ? (c * 4608 + nl * 72 + d) : (2 * 4608 + d * 72 + nl);
            outs[off] = (f16)(acc[jt][r] + bias);
        }
    }
    __syncthreads();

    {
        int rr = tid >> 2, ch = (tid & 3) * 16;
        f16x8 v0, v1;
        v0 = *(const f16x8*)(&outs[rr * 72 + ch]);
        v1 = *(const f16x8*)(&outs[rr * 72 + ch + 8]);
        f16* qd = Qb + ((size_t)bh * SEQ + n0 + rr) * HD + ch;
        *(f16x8*)qd = v0; *(f16x8*)(qd + 8) = v1;
        v0 = *(const f16x8*)(&outs[4608 + rr * 72 + ch]);
        v1 = *(const f16x8*)(&outs[4608 + rr * 72 + ch + 8]);
        f16* kd = Kb + ((size_t)bh * SEQ + n0 + rr) * HD + ch;
        *(f16x8*)kd = v0; *(f16x8*)(kd + 8) = v1;
        v0 = *(const f16x8*)(&outs[9216 + rr * 72 + ch]);
        v1 = *(const f16x8*)(&outs[9216 + rr * 72 + ch + 8]);
        f16* vd = Vtb + ((size_t)bh * HD + rr) * SEQ + n0 + ch;
        *(f16x8*)vd = v0; *(f16x8*)(vd + 8) = v1;
    }
}

// ---------------------------------------------------------------------------
// Kernel 3: flash attention, S^T formulation.
//   S^T = K·Q^T  (per-lane softmax state, 4 shuffles/kt)
//   O^T = V^T·P^T (P^T via tiny per-wave LDS round-trip)
// K/V fragments loaded DIRECTLY from global (L1/L2-hot) — no staging,
// no __syncthreads anywhere. Wave = 32 qrows (2 n-tiles) x 64 keys/kt.
// ---------------------------------------------------------------------------
__global__ __launch_bounds__(256, 4) void flash_kernel(const f16* __restrict__ Qb,
                                                       const f16* __restrict__ Kb,
                                                       const f16* __restrict__ Vtb,
                                                       f16* __restrict__ attn) {
    __shared__ __align__(16) f16 p_lds[4][2][16][72];   // [wave][ntile][qrow16][keys]

    const int qt   = blockIdx.x;          // 0..7  (128 qrows/block)
    const int h    = blockIdx.y;
    const int b    = blockIdx.z;
    const int bh   = b * NH + h;
    const int tid  = threadIdx.x;
    const int wave = tid >> 6, lane = tid & 63;
    const int quad = lane >> 4, l16 = lane & 15;

    // Q fragments (B-operand): lane holds Q[qrow=l16][d=quad*8+j]
    const f16* Qp = Qb + ((size_t)bh * SEQ + qt * 128 + wave * 32) * HD;
    f16x8 qf[2][2];
    for (int j = 0; j < 2; j++)
        for (int ss = 0; ss < 2; ss++)
            qf[j][ss] = *(const f16x8*)(Qp + (size_t)(j * 16 + l16) * HD + ss * 32 + quad * 8);

    const f16* Kp = Kb + (size_t)bh * SEQ * HD + (size_t)l16 * HD + quad * 8;
    const f16* Vp = Vtb + (size_t)bh * HD * SEQ + (size_t)l16 * SEQ + quad * 8;

    float m_st[2] = {-INFINITY, -INFINITY};
    float l_st[2] = {0.f, 0.f};
    f32x4 o[4][2];                        // [mt over d][ntile]
    f32x4 z = {0.f, 0.f, 0.f, 0.f};
    for (int mt = 0; mt < 4; mt++) { o[mt][0] = z; o[mt][1] = z; }

    for (int kt = 0; kt < SEQ / 64; kt++) {
        // ---- S^T = K · Q^T : 4 key m-tiles x 2 qrow n-tiles ----
        const f16* kb = Kp + (size_t)(kt * 64) * HD;
        f32x4 s[4][2];
        for (int ct = 0; ct < 4; ct++) {
            f16x8 ka = *(const f16x8*)(kb + (size_t)(ct * 16) * HD);
            f16x8 kc = *(const f16x8*)(kb + (size_t)(ct * 16) * HD + 32);
            s[ct][0] = __builtin_amdgcn_mfma_f32_16x16x32_f16(ka, qf[0][0], z, 0, 0, 0);
            s[ct][0] = __builtin_amdgcn_mfma_f32_16x16x32_f16(kc, qf[0][1], s[ct][0], 0, 0, 0);
            s[ct][1] = __builtin_amdgcn_mfma_f32_16x16x32_f16(ka, qf[1][0], z, 0, 0, 0);
            s[ct][1] = __builtin_amdgcn_mfma_f32_16x16x32_f16(kc, qf[1][1], s[ct][1], 0, 0, 0);
        }

        // prefetch V chunk c=0 while softmax runs
        f16x8 va0[4];
        for (int mt = 0; mt < 4; mt++)
            va0[mt] = *(const f16x8*)(Vp + (size_t)(mt * 16) * SEQ + kt * 64);

        // ---- online softmax (per-lane state: col = qrow = l16) ----
        for (int j = 0; j < 2; j++) {
            float mx = fmaxf(fmaxf(fmaxf(s[0][j][0], s[0][j][1]), fmaxf(s[0][j][2], s[0][j][3])),
                             fmaxf(fmaxf(s[1][j][0], s[1][j][1]), fmaxf(s[1][j][2], s[1][j][3])));
            mx = fmaxf(mx, fmaxf(fmaxf(fmaxf(s[2][j][0], s[2][j][1]), fmaxf(s[2][j][2], s[2][j][3])),
                                 fmaxf(fmaxf(s[3][j][0], s[3][j][1]), fmaxf(s[3][j][2], s[3][j][3]))));
            mx = fmaxf(mx, __shfl_xor(mx, 16, 64));
            mx = fmaxf(mx, __shfl_xor(mx, 32, 64));
            float mn = fmaxf(m_st[j], mx);
            float al = __expf(m_st[j] - mn);
            m_st[j] = mn;
            float rs = 0.f;
            for (int ct = 0; ct < 4; ct++)
                for (int r = 0; r < 4; r++) {
                    float p = __expf(s[ct][j][r] - mn);
                    s[ct][j][r] = p;
                    rs += p;
                }
            rs += __shfl_xor(rs, 16, 64);
            rs += __shfl_xor(rs, 32, 64);
            l_st[j] = l_st[j] * al + rs;
            for (int mt = 0; mt < 4; mt++) o[mt][j] *= al;

            // pack P^T into per-wave LDS: [qrow=l16][key], b64 writes
            for (int ct = 0; ct < 4; ct++) {
                f16x4 w = {(f16)s[ct][j][0], (f16)s[ct][j][1],
                           (f16)s[ct][j][2], (f16)s[ct][j][3]};
                *(f16x4*)(&p_lds[wave][j][l16][ct * 16 + quad * 4]) = w;
            }
        }

        // prefetch V chunk c=1
        f16x8 va1[4];
        for (int mt = 0; mt < 4; mt++)
            va1[mt] = *(const f16x8*)(Vp + (size_t)(mt * 16) * SEQ + kt * 64 + 32);

        __asm__ volatile("s_waitcnt lgkmcnt(0)" ::: "memory");

        // ---- O^T += V^T · P^T ----
        {
            f16x8 p0 = *(const f16x8*)(&p_lds[wave][0][l16][quad * 8]);
            f16x8 p1 = *(const f16x8*)(&p_lds[wave][1][l16][quad * 8]);
            for (int mt = 0; mt < 4; mt++) {
                o[mt][0] = __builtin_amdgcn_mfma_f32_16x16x32_f16(va0[mt], p0, o[mt][0], 0, 0, 0);
                o[mt][1] = __builtin_amdgcn_mfma_f32_16x16x32_f16(va0[mt], p1, o[mt][1], 0, 0, 0);
            }
            p0 = *(const f16x8*)(&p_lds[wave][0][l16][32 + quad * 8]);
            p1 = *(const f16x8*)(&p_lds[wave][1][l16][32 + quad * 8]);
            for (int mt = 0; mt < 4; mt++) {
                o[mt][0] = __builtin_amdgcn_mfma_f32_16x16x32_f16(va1[mt], p0, o[mt][0], 0, 0, 0);
                o[mt][1] = __builtin_amdgcn_mfma_f32_16x16x32_f16(va1[mt], p1, o[mt][1], 0, 0, 0);
            }
        }
    }

    // epilogue: attn[b][n][h*64+d], post-softmax /8 folded in
    for (int j = 0; j < 2; j++) {
        float sc = 1.0f / (8.0f * l_st[j]);
        int n = qt * 128 + wave * 32 + j * 16 + l16;
        f16* op = attn + ((size_t)b * SEQ + n) * HID + h * HD + quad * 4;
        for (int mt = 0; mt < 4; mt++) {
            f16x4 w = {(f16)(o[mt][j][0] * sc), (f16)(o[mt][j][1] * sc),
                       (f16)(o[mt][j][2] * sc), (f16)(o[mt][j][3] * sc)};
            *(f16x4*)(op + mt * 16) = w;
        }
    }
}

// ---------------------------------------------------------------------------
// Kernel 4: output projection. attn (32768 x 512) @ w_proj (512 x 64) + b.
// ---------------------------------------------------------------------------
__global__ __launch_bounds__(256) void proj_kernel(const f16* __restrict__ attn,
                                                   const f16* __restrict__ wTp,
                                                   const float* __restrict__ b_proj,
                                                   float* __restrict__ out) {
    __shared__ __align__(16) f16 a_lds[64][72];
    __shared__ __align__(16) f16 w_lds[64][72];

    const int blk  = blockIdx.x;
    const int tid  = threadIdx.x;
    const int wave = tid >> 6, lane = tid & 63;
    const int quad = lane >> 4, l16 = lane & 15;

    f32x4 acc[4];
    f32x4 z = {0.f, 0.f, 0.f, 0.f};
    for (int ct = 0; ct < 4; ct++) acc[ct] = z;

    for (int kt = 0; kt < 8; kt++) {
        __syncthreads();
        for (int p = 0; p < 2; p++) {
            int t = tid + p * 256;
            int row = t >> 3, col = (t & 7) * 8;
            *(f16x8*)(&a_lds[row][col]) =
                *(const f16x8*)(attn + ((size_t)(blk * 64 + row)) * HID + kt * 64 + col);
            *(f16x8*)(&w_lds[row][col]) =
                *(const f16x8*)(wTp + (size_t)row * HID + kt * 64 + col);
        }
        __syncthreads();
        for (int ss = 0; ss < 2; ss++) {
            f16x8 af = *(const f16x8*)(&a_lds[wave * 16 + l16][quad * 8 + ss * 32]);
            for (int ct = 0; ct < 4; ct++) {
                f16x8 bf = *(const f16x8*)(&w_lds[ct * 16 + l16][quad * 8 + ss * 32]);
                acc[ct] = __builtin_amdgcn_mfma_f32_16x16x32_f16(af, bf, acc[ct], 0, 0, 0);
            }
        }
    }

    for (int ct = 0; ct < 4; ct++) {
        float bias = b_proj[ct * 16 + l16];
        for (int r = 0; r < 4; r++) {
            int row = blk * 64 + wave * 16 + quad * 4 + r;
            out[(size_t)row * HD + ct * 16 + l16] = acc[ct][r] + bias;
        }
    }
}

// ---------------------------------------------------------------------------
extern "C" void kernel_launch(void* const* d_in, const int* in_sizes, int n_in,
                              void* d_out, int out_size, void* d_ws, size_t ws_size,
                              hipStream_t stream) {
    (void)in_sizes; (void)n_in; (void)out_size; (void)ws_size;
    const float* x      = (const float*)d_in[0];
    const float* w_qkv  = (const float*)d_in[1];
    const float* b_qkv  = (const float*)d_in[2];
    const float* w_proj = (const float*)d_in[3];
    const float* b_proj = (const float*)d_in[4];
    float* out = (float*)d_out;

    char* ws = (char*)d_ws;
    const size_t QKV_EL = (size_t)BATCH * NH * SEQ * HD;
    f16* wTq  = (f16*)(ws);
    f16* wTp  = (f16*)(ws + 196608);
    f16* Qb   = (f16*)(ws + 262144);
    f16* Kb   = (f16*)(ws + 262144 + 2 * QKV_EL);
    f16* Vtb  = (f16*)(ws + 262144 + 4 * QKV_EL);
    f16* attn = (f16*)(ws + 262144 + 6 * QKV_EL);

    transpose_w<<<512, 256, 0, stream>>>(w_qkv, w_proj, wTq, wTp);
    qkv_kernel<<<dim3(16, BATCH * NH), 256, 0, stream>>>(x, wTq, b_qkv, Qb, Kb, Vtb);
    flash_kernel<<<dim3(8, NH, BATCH), 256, 0, stream>>>(Qb, Kb, Vtb, attn);
    proj_kernel<<<512, 256, 0, stream>>>(attn, wTp, b_proj, out);
}

// Round 5
// 215.636 us; speedup vs baseline: 1.8741x; 1.8741x over previous
//
#include <hip/hip_runtime.h>
#include <hip/hip_bf16.h>

#define SEQ 1024
#define NH 8
#define HD 64
#define HID 512
#define BATCH 32
#define LOG2E 1.44269504f
#define KST 68              // LDS row stride in f16: 34 dwords == 2 (mod 4) -> b64 ops bank-balanced

typedef _Float16 f16;
typedef f16 f16x4 __attribute__((ext_vector_type(4)));
typedef f16 f16x8 __attribute__((ext_vector_type(8)));
typedef float f32x4 __attribute__((ext_vector_type(4)));

#define MFMA16 __builtin_amdgcn_mfma_f32_16x16x32_f16
#define EXP2F  __builtin_amdgcn_exp2f

// 8B-granular LDS load/store (rows are 8B-aligned with stride 68)
__device__ __forceinline__ f16x8 ld8(const f16* p) {
    f16x4 a = *(const f16x4*)p;
    f16x4 b = *(const f16x4*)(p + 4);
    return __builtin_shufflevector(a, b, 0, 1, 2, 3, 4, 5, 6, 7);
}
__device__ __forceinline__ void st8(f16* p, f16x8 v) {
    *(f16x4*)p       = __builtin_shufflevector(v, v, 0, 1, 2, 3);
    *(f16x4*)(p + 4) = __builtin_shufflevector(v, v, 4, 5, 6, 7);
}

// ---------------------------------------------------------------------------
// Kernel 1: transpose weights to f16, k-contiguous (B-operand layout)
// ---------------------------------------------------------------------------
__global__ __launch_bounds__(256) void transpose_w(const float* __restrict__ wq,
                                                   const float* __restrict__ wp,
                                                   f16* __restrict__ wTq,
                                                   f16* __restrict__ wTp) {
    int flat = blockIdx.x * 256 + threadIdx.x;
    if (flat < 64 * 1536) {
        int e = flat / 1536, j = flat % 1536;
        wTq[(size_t)j * 64 + e] = (f16)wq[flat];
    } else {
        int f2 = flat - 64 * 1536;
        int k = f2 / 64, n = f2 % 64;
        wTp[(size_t)n * 512 + k] = (f16)wp[f2];
    }
}

// ---------------------------------------------------------------------------
// Kernel 2: QKV projection (MFMA) + LDS-bounce coalesced stores.
// Q is pre-scaled by log2(e) IN FP32 (flash uses exp2) — no extra rounding.
//   Qb[bh][n][d], Kb[bh][n][d], Vtb[bh][d][n]
// ---------------------------------------------------------------------------
__global__ __launch_bounds__(256) void qkv_kernel(const float* __restrict__ x,
                                                  const f16* __restrict__ wTq,
                                                  const float* __restrict__ b_qkv,
                                                  f16* __restrict__ Qb,
                                                  f16* __restrict__ Kb,
                                                  f16* __restrict__ Vtb) {
    __shared__ __align__(16) char smem[36864];
    f16* xs = (f16*)smem;                  // [64][72]
    f16* wsh = (f16*)(smem + 9216);        // [192][72]
    f16* outs = (f16*)smem;                // [3][64][72]

    const int n0   = blockIdx.x * 64;
    const int bh   = blockIdx.y;
    const int b    = bh >> 3, h = bh & 7;
    const int tid  = threadIdx.x;
    const int wave = tid >> 6, lane = tid & 63;
    const int quad = lane >> 4, l16 = lane & 15;

    for (int p = 0; p < 2; p++) {
        int t = tid + p * 256;
        int row = t >> 3, col = (t & 7) * 8;
        const float* src = x + ((size_t)(b * SEQ + n0 + row)) * 64 + col;
        float4 a0 = *(const float4*)src;
        float4 a1 = *(const float4*)(src + 4);
        f16x8 v = {(f16)a0.x, (f16)a0.y, (f16)a0.z, (f16)a0.w,
                   (f16)a1.x, (f16)a1.y, (f16)a1.z, (f16)a1.w};
        *(f16x8*)(&xs[row * 72 + col]) = v;
    }
    for (int p = 0; p < 6; p++) {
        int row = p * 32 + (tid >> 3), col = (tid & 7) * 8;
        *(f16x8*)(&wsh[row * 72 + col]) =
            *(const f16x8*)(wTq + (size_t)(h * 192 + row) * 64 + col);
    }
    __syncthreads();

    f16x8 af[2];
    af[0] = *(const f16x8*)(&xs[(wave * 16 + l16) * 72 + quad * 8]);
    af[1] = *(const f16x8*)(&xs[(wave * 16 + l16) * 72 + quad * 8 + 32]);

    f32x4 acc[12];
    f32x4 z = {0.f, 0.f, 0.f, 0.f};
    for (int jt = 0; jt < 12; jt++) acc[jt] = z;
    for (int jt = 0; jt < 12; jt++)
        for (int ss = 0; ss < 2; ss++) {
            f16x8 bf = *(const f16x8*)(&wsh[(jt * 16 + l16) * 72 + quad * 8 + ss * 32]);
            acc[jt] = MFMA16(af[ss], bf, acc[jt], 0, 0, 0);
        }

    __syncthreads();   // done reading xs/wsh; reuse as outs

    for (int jt = 0; jt < 12; jt++) {
        int jl = jt * 16 + l16;
        float bias = b_qkv[h * 192 + jl];
        int d = jl / 3, c = jl - 3 * d;
        float scl = (c == 0) ? LOG2E : 1.0f;
        for (int r = 0; r < 4; r++) {
            int nl = wave * 16 + quad * 4 + r;
            int off = (c < 2) ? (c * 4608 + nl * 72 + d) : (2 * 4608 + d * 72 + nl);
            outs[off] = (f16)((acc[jt][r] + bias) * scl);
        }
    }
    __syncthreads();

    {
        int rr = tid >> 2, ch = (tid & 3) * 16;
        f16x8 v0, v1;
        v0 = *(const f16x8*)(&outs[rr * 72 + ch]);
        v1 = *(const f16x8*)(&outs[rr * 72 + ch + 8]);
        f16* qd = Qb + ((size_t)bh * SEQ + n0 + rr) * HD + ch;
        *(f16x8*)qd = v0; *(f16x8*)(qd + 8) = v1;
        v0 = *(const f16x8*)(&outs[4608 + rr * 72 + ch]);
        v1 = *(const f16x8*)(&outs[4608 + rr * 72 + ch + 8]);
        f16* kd = Kb + ((size_t)bh * SEQ + n0 + rr) * HD + ch;
        *(f16x8*)kd = v0; *(f16x8*)(kd + 8) = v1;
        v0 = *(const f16x8*)(&outs[9216 + rr * 72 + ch]);
        v1 = *(const f16x8*)(&outs[9216 + rr * 72 + ch + 8]);
        f16* vd = Vtb + ((size_t)bh * HD + rr) * SEQ + n0 + ch;
        *(f16x8*)vd = v0; *(f16x8*)(vd + 8) = v1;
    }
}

// ---------------------------------------------------------------------------
// Kernel 3: flash attention.
//   S^T = K·Q^T (per-lane softmax state), O^T = V^T·P^T (P^T via LDS bounce)
//   K/V double-buffered in LDS: prefetch kt+1 to regs BEFORE compute on kt,
//   write to other buffer after, single barrier per iteration.
//   All LDS rows stride-68 f16, all DS ops b64 — bank-balanced.
//   Q arrives pre-scaled by log2e -> softmax in exp2 domain.
// Block: 256 thr = 4 waves x 32 qrows; grid (bh=256, qt=8).
// ---------------------------------------------------------------------------
__global__ __launch_bounds__(256, 3) void flash_kernel(const f16* __restrict__ Qb,
                                                       const f16* __restrict__ Kb,
                                                       const f16* __restrict__ Vtb,
                                                       f16* __restrict__ attn) {
    __shared__ __align__(16) f16 kv_lds[2][2][64 * KST];   // [buf][K/V][row*KST]
    __shared__ __align__(16) f16 p_lds[4][2][16 * KST];    // [wave][ntile][qrow*KST]

    const int bh   = blockIdx.x;          // same-bh blocks -> same XCD (id%8)
    const int qt   = blockIdx.y;
    const int b    = bh >> 3, h = bh & 7;
    const int tid  = threadIdx.x;
    const int wave = tid >> 6, lane = tid & 63;
    const int quad = lane >> 4, l16 = lane & 15;

    const f16* kg = Kb  + (size_t)bh * SEQ * HD;
    const f16* vg = Vtb + (size_t)bh * HD * SEQ;
    const int srow = tid >> 2, scol = (tid & 3) * 16;

    // stage kt = 0
    {
        const f16* kp = kg + (size_t)srow * HD + scol;
        const f16* vp = vg + (size_t)srow * SEQ + scol;
        f16x8 k0 = *(const f16x8*)kp, k1 = *(const f16x8*)(kp + 8);
        f16x8 v0 = *(const f16x8*)vp, v1 = *(const f16x8*)(vp + 8);
        st8(&kv_lds[0][0][srow * KST + scol], k0);
        st8(&kv_lds[0][0][srow * KST + scol + 8], k1);
        st8(&kv_lds[0][1][srow * KST + scol], v0);
        st8(&kv_lds[0][1][srow * KST + scol + 8], v1);
    }

    // Q fragments (B-operand): lane holds Q[qrow=l16][d=quad*8+j], pre-scaled
    const f16* Qp = Qb + ((size_t)bh * SEQ + qt * 128 + wave * 32) * HD;
    f16x8 qf[2][2];
    for (int j = 0; j < 2; j++)
        for (int ss = 0; ss < 2; ss++)
            qf[j][ss] = *(const f16x8*)(Qp + (size_t)(j * 16 + l16) * HD + ss * 32 + quad * 8);

    float m_st[2] = {-INFINITY, -INFINITY};
    float l_st[2] = {0.f, 0.f};
    f32x4 o[4][2];
    f32x4 z = {0.f, 0.f, 0.f, 0.f};
    for (int mt = 0; mt < 4; mt++) { o[mt][0] = z; o[mt][1] = z; }

    __syncthreads();

    for (int kt = 0; kt < SEQ / 64; kt++) {
        const int buf = kt & 1;

        // prefetch next K/V tile into registers (consumed after compute)
        f16x8 pk0, pk1, pv0, pv1;
        if (kt < SEQ / 64 - 1) {
            const f16* kn = kg + (size_t)((kt + 1) * 64 + srow) * HD + scol;
            const f16* vn = vg + (size_t)srow * SEQ + (kt + 1) * 64 + scol;
            pk0 = *(const f16x8*)kn; pk1 = *(const f16x8*)(kn + 8);
            pv0 = *(const f16x8*)vn; pv1 = *(const f16x8*)(vn + 8);
        }

        const f16* ks = &kv_lds[buf][0][0];
        const f16* vs = &kv_lds[buf][1][0];

        // ---- S^T = K · Q^T ----
        f32x4 s[4][2];
        for (int ct = 0; ct < 4; ct++) {
            f16x8 ka = ld8(ks + (ct * 16 + l16) * KST + quad * 8);
            f16x8 kc = ld8(ks + (ct * 16 + l16) * KST + quad * 8 + 32);
            s[ct][0] = MFMA16(ka, qf[0][0], z, 0, 0, 0);
            s[ct][0] = MFMA16(kc, qf[0][1], s[ct][0], 0, 0, 0);
            s[ct][1] = MFMA16(ka, qf[1][0], z, 0, 0, 0);
            s[ct][1] = MFMA16(kc, qf[1][1], s[ct][1], 0, 0, 0);
        }

        // ---- online softmax, exp2 domain (per-lane state, col=qrow=l16) ----
        for (int j = 0; j < 2; j++) {
            float mx = fmaxf(fmaxf(fmaxf(s[0][j][0], s[0][j][1]), fmaxf(s[0][j][2], s[0][j][3])),
                             fmaxf(fmaxf(s[1][j][0], s[1][j][1]), fmaxf(s[1][j][2], s[1][j][3])));
            mx = fmaxf(mx, fmaxf(fmaxf(fmaxf(s[2][j][0], s[2][j][1]), fmaxf(s[2][j][2], s[2][j][3])),
                                 fmaxf(fmaxf(s[3][j][0], s[3][j][1]), fmaxf(s[3][j][2], s[3][j][3]))));
            mx = fmaxf(mx, __shfl_xor(mx, 16, 64));
            mx = fmaxf(mx, __shfl_xor(mx, 32, 64));
            float mn = fmaxf(m_st[j], mx);
            float al = EXP2F(m_st[j] - mn);
            m_st[j] = mn;
            float rs = 0.f;
            for (int ct = 0; ct < 4; ct++)
                for (int r = 0; r < 4; r++) {
                    float p = EXP2F(s[ct][j][r] - mn);
                    s[ct][j][r] = p;
                    rs += p;
                }
            rs += __shfl_xor(rs, 16, 64);
            rs += __shfl_xor(rs, 32, 64);
            l_st[j] = l_st[j] * al + rs;
            for (int mt = 0; mt < 4; mt++) o[mt][j] *= al;

            // P^T -> per-wave LDS (b64 writes, bank-balanced)
            for (int ct = 0; ct < 4; ct++) {
                f16x4 w = {(f16)s[ct][j][0], (f16)s[ct][j][1],
                           (f16)s[ct][j][2], (f16)s[ct][j][3]};
                *(f16x4*)(&p_lds[wave][j][l16 * KST + ct * 16 + quad * 4]) = w;
            }
        }

        __asm__ volatile("s_waitcnt lgkmcnt(0)" ::: "memory");

        // ---- O^T += V^T · P^T ----
        {
            f16x8 va[4];
            for (int mt = 0; mt < 4; mt++)
                va[mt] = ld8(vs + (mt * 16 + l16) * KST + quad * 8);
            f16x8 p0 = ld8(&p_lds[wave][0][l16 * KST + quad * 8]);
            f16x8 p1 = ld8(&p_lds[wave][1][l16 * KST + quad * 8]);
            for (int mt = 0; mt < 4; mt++) {
                o[mt][0] = MFMA16(va[mt], p0, o[mt][0], 0, 0, 0);
                o[mt][1] = MFMA16(va[mt], p1, o[mt][1], 0, 0, 0);
            }
            for (int mt = 0; mt < 4; mt++)
                va[mt] = ld8(vs + (mt * 16 + l16) * KST + quad * 8 + 32);
            p0 = ld8(&p_lds[wave][0][l16 * KST + quad * 8 + 32]);
            p1 = ld8(&p_lds[wave][1][l16 * KST + quad * 8 + 32]);
            for (int mt = 0; mt < 4; mt++) {
                o[mt][0] = MFMA16(va[mt], p0, o[mt][0], 0, 0, 0);
                o[mt][1] = MFMA16(va[mt], p1, o[mt][1], 0, 0, 0);
            }
        }

        // write prefetched tile to the other buffer
        if (kt < SEQ / 64 - 1) {
            const int nb = buf ^ 1;
            st8(&kv_lds[nb][0][srow * KST + scol], pk0);
            st8(&kv_lds[nb][0][srow * KST + scol + 8], pk1);
            st8(&kv_lds[nb][1][srow * KST + scol], pv0);
            st8(&kv_lds[nb][1][srow * KST + scol + 8], pv1);
        }
        __syncthreads();
    }

    // epilogue: attn[b][n][h*64+d], post-softmax /8 folded in
    for (int j = 0; j < 2; j++) {
        float sc = 1.0f / (8.0f * l_st[j]);
        int n = qt * 128 + wave * 32 + j * 16 + l16;
        f16* op = attn + ((size_t)b * SEQ + n) * HID + h * HD + quad * 4;
        for (int mt = 0; mt < 4; mt++) {
            f16x4 w = {(f16)(o[mt][j][0] * sc), (f16)(o[mt][j][1] * sc),
                       (f16)(o[mt][j][2] * sc), (f16)(o[mt][j][3] * sc)};
            *(f16x4*)(op + mt * 16) = w;
        }
    }
}

// ---------------------------------------------------------------------------
// Kernel 4: output projection. attn (32768 x 512) @ w_proj (512 x 64) + b.
// ---------------------------------------------------------------------------
__global__ __launch_bounds__(256) void proj_kernel(const f16* __restrict__ attn,
                                                   const f16* __restrict__ wTp,
                                                   const float* __restrict__ b_proj,
                                                   float* __restrict__ out) {
    __shared__ __align__(16) f16 a_lds[64][72];
    __shared__ __align__(16) f16 w_lds[64][72];

    const int blk  = blockIdx.x;
    const int tid  = threadIdx.x;
    const int wave = tid >> 6, lane = tid & 63;
    const int quad = lane >> 4, l16 = lane & 15;

    f32x4 acc[4];
    f32x4 z = {0.f, 0.f, 0.f, 0.f};
    for (int ct = 0; ct < 4; ct++) acc[ct] = z;

    for (int kt = 0; kt < 8; kt++) {
        __syncthreads();
        for (int p = 0; p < 2; p++) {
            int t = tid + p * 256;
            int row = t >> 3, col = (t & 7) * 8;
            *(f16x8*)(&a_lds[row][col]) =
                *(const f16x8*)(attn + ((size_t)(blk * 64 + row)) * HID + kt * 64 + col);
            *(f16x8*)(&w_lds[row][col]) =
                *(const f16x8*)(wTp + (size_t)row * HID + kt * 64 + col);
        }
        __syncthreads();
        for (int ss = 0; ss < 2; ss++) {
            f16x8 af = *(const f16x8*)(&a_lds[wave * 16 + l16][quad * 8 + ss * 32]);
            for (int ct = 0; ct < 4; ct++) {
                f16x8 bf = *(const f16x8*)(&w_lds[ct * 16 + l16][quad * 8 + ss * 32]);
                acc[ct] = MFMA16(af, bf, acc[ct], 0, 0, 0);
            }
        }
    }

    for (int ct = 0; ct < 4; ct++) {
        float bias = b_proj[ct * 16 + l16];
        for (int r = 0; r < 4; r++) {
            int row = blk * 64 + wave * 16 + quad * 4 + r;
            out[(size_t)row * HD + ct * 16 + l16] = acc[ct][r] + bias;
        }
    }
}

// ---------------------------------------------------------------------------
extern "C" void kernel_launch(void* const* d_in, const int* in_sizes, int n_in,
                              void* d_out, int out_size, void* d_ws, size_t ws_size,
                              hipStream_t stream) {
    (void)in_sizes; (void)n_in; (void)out_size; (void)ws_size;
    const float* x      = (const float*)d_in[0];
    const float* w_qkv  = (const float*)d_in[1];
    const float* b_qkv  = (const float*)d_in[2];
    const float* w_proj = (const float*)d_in[3];
    const float* b_proj = (const float*)d_in[4];
    float* out = (float*)d_out;

    char* ws = (char*)d_ws;
    const size_t QKV_EL = (size_t)BATCH * NH * SEQ * HD;
    f16* wTq  = (f16*)(ws);
    f16* wTp  = (f16*)(ws + 196608);
    f16* Qb   = (f16*)(ws + 262144);
    f16* Kb   = (f16*)(ws + 262144 + 2 * QKV_EL);
    f16* Vtb  = (f16*)(ws + 262144 + 4 * QKV_EL);
    f16* attn = (f16*)(ws + 262144 + 6 * QKV_EL);

    transpose_w<<<512, 256, 0, stream>>>(w_qkv, w_proj, wTq, wTp);
    qkv_kernel<<<dim3(16, BATCH * NH), 256, 0, stream>>>(x, wTq, b_qkv, Qb, Kb, Vtb);
    flash_kernel<<<dim3(256, 8), 256, 0, stream>>>(Qb, Kb, Vtb, attn);
    proj_kernel<<<512, 256, 0, stream>>>(attn, wTp, b_proj, out);
}

// Round 6
// 213.444 us; speedup vs baseline: 1.8934x; 1.0103x over previous
//
#include <hip/hip_runtime.h>
#include <hip/hip_bf16.h>

#define SEQ 1024
#define NH 8
#define HD 64
#define HID 512
#define BATCH 32
#define LOG2E 1.44269504f
#define KST 68              // LDS row stride in f16: 34 dwords == 2 (mod 4) -> b64 ops bank-balanced

typedef _Float16 f16;
typedef f16 f16x4 __attribute__((ext_vector_type(4)));
typedef f16 f16x8 __attribute__((ext_vector_type(8)));
typedef float f32x4 __attribute__((ext_vector_type(4)));
typedef __fp16 h16x2 __attribute__((ext_vector_type(2)));

#define MFMA16 __builtin_amdgcn_mfma_f32_16x16x32_f16
#define EXP2F  __builtin_amdgcn_exp2f

// 8B-granular LDS load/store (rows are 8B-aligned with stride 68)
__device__ __forceinline__ f16x8 ld8(const f16* p) {
    f16x4 a = *(const f16x4*)p;
    f16x4 b = *(const f16x4*)(p + 4);
    return __builtin_shufflevector(a, b, 0, 1, 2, 3, 4, 5, 6, 7);
}
__device__ __forceinline__ void st8(f16* p, f16x8 v) {
    *(f16x4*)p       = __builtin_shufflevector(v, v, 0, 1, 2, 3);
    *(f16x4*)(p + 4) = __builtin_shufflevector(v, v, 4, 5, 6, 7);
}

// ---------------------------------------------------------------------------
// Kernel 1: transpose weights to f16, k-contiguous (B-operand layout)
// ---------------------------------------------------------------------------
__global__ __launch_bounds__(256) void transpose_w(const float* __restrict__ wq,
                                                   const float* __restrict__ wp,
                                                   f16* __restrict__ wTq,
                                                   f16* __restrict__ wTp) {
    int flat = blockIdx.x * 256 + threadIdx.x;
    if (flat < 64 * 1536) {
        int e = flat / 1536, j = flat % 1536;
        wTq[(size_t)j * 64 + e] = (f16)wq[flat];
    } else {
        int f2 = flat - 64 * 1536;
        int k = f2 / 64, n = f2 % 64;
        wTp[(size_t)n * 512 + k] = (f16)wp[f2];
    }
}

// ---------------------------------------------------------------------------
// Kernel 2: QKV projection (MFMA) + LDS-bounce coalesced stores.
// blockIdx.y decode b=y&31,h=y>>5: the 8 h-siblings sharing an x-tile get
// ids 32 apart -> same id%8 -> same XCD -> x-tile L2 reuse.
// Q pre-scaled by log2(e) in fp32 (flash softmax runs in exp2 domain).
//   Qb[bh][n][d], Kb[bh][n][d], Vtb[bh][d][n]
// ---------------------------------------------------------------------------
__global__ __launch_bounds__(256) void qkv_kernel(const float* __restrict__ x,
                                                  const f16* __restrict__ wTq,
                                                  const float* __restrict__ b_qkv,
                                                  f16* __restrict__ Qb,
                                                  f16* __restrict__ Kb,
                                                  f16* __restrict__ Vtb) {
    __shared__ __align__(16) char smem[36864];
    f16* xs = (f16*)smem;                  // [64][72]
    f16* wsh = (f16*)(smem + 9216);        // [192][72]
    f16* outs = (f16*)smem;                // [3][64][72]

    const int n0   = blockIdx.x * 64;
    const int y    = blockIdx.y;
    const int b    = y & 31, h = y >> 5;
    const int bh   = b * NH + h;
    const int tid  = threadIdx.x;
    const int wave = tid >> 6, lane = tid & 63;
    const int quad = lane >> 4, l16 = lane & 15;

    for (int p = 0; p < 2; p++) {
        int t = tid + p * 256;
        int row = t >> 3, col = (t & 7) * 8;
        const float* src = x + ((size_t)(b * SEQ + n0 + row)) * 64 + col;
        float4 a0 = *(const float4*)src;
        float4 a1 = *(const float4*)(src + 4);
        f16x8 v = {(f16)a0.x, (f16)a0.y, (f16)a0.z, (f16)a0.w,
                   (f16)a1.x, (f16)a1.y, (f16)a1.z, (f16)a1.w};
        *(f16x8*)(&xs[row * 72 + col]) = v;
    }
    for (int p = 0; p < 6; p++) {
        int row = p * 32 + (tid >> 3), col = (tid & 7) * 8;
        *(f16x8*)(&wsh[row * 72 + col]) =
            *(const f16x8*)(wTq + (size_t)(h * 192 + row) * 64 + col);
    }
    __syncthreads();

    f16x8 af[2];
    af[0] = *(const f16x8*)(&xs[(wave * 16 + l16) * 72 + quad * 8]);
    af[1] = *(const f16x8*)(&xs[(wave * 16 + l16) * 72 + quad * 8 + 32]);

    f32x4 acc[12];
    f32x4 z = {0.f, 0.f, 0.f, 0.f};
    for (int jt = 0; jt < 12; jt++) acc[jt] = z;
    for (int jt = 0; jt < 12; jt++)
        for (int ss = 0; ss < 2; ss++) {
            f16x8 bf = *(const f16x8*)(&wsh[(jt * 16 + l16) * 72 + quad * 8 + ss * 32]);
            acc[jt] = MFMA16(af[ss], bf, acc[jt], 0, 0, 0);
        }

    __syncthreads();   // done reading xs/wsh; reuse as outs

    for (int jt = 0; jt < 12; jt++) {
        int jl = jt * 16 + l16;
        float bias = b_qkv[h * 192 + jl];
        int d = jl / 3, c = jl - 3 * d;
        float scl = (c == 0) ? LOG2E : 1.0f;
        for (int r = 0; r < 4; r++) {
            int nl = wave * 16 + quad * 4 + r;
            int off = (c < 2) ? (c * 4608 + nl * 72 + d) : (2 * 4608 + d * 72 + nl);
            outs[off] = (f16)((acc[jt][r] + bias) * scl);
        }
    }
    __syncthreads();

    {
        int rr = tid >> 2, ch = (tid & 3) * 16;
        f16x8 v0, v1;
        v0 = *(const f16x8*)(&outs[rr * 72 + ch]);
        v1 = *(const f16x8*)(&outs[rr * 72 + ch + 8]);
        f16* qd = Qb + ((size_t)bh * SEQ + n0 + rr) * HD + ch;
        *(f16x8*)qd = v0; *(f16x8*)(qd + 8) = v1;
        v0 = *(const f16x8*)(&outs[4608 + rr * 72 + ch]);
        v1 = *(const f16x8*)(&outs[4608 + rr * 72 + ch + 8]);
        f16* kd = Kb + ((size_t)bh * SEQ + n0 + rr) * HD + ch;
        *(f16x8*)kd = v0; *(f16x8*)(kd + 8) = v1;
        v0 = *(const f16x8*)(&outs[9216 + rr * 72 + ch]);
        v1 = *(const f16x8*)(&outs[9216 + rr * 72 + ch + 8]);
        f16* vd = Vtb + ((size_t)bh * HD + rr) * SEQ + n0 + ch;
        *(f16x8*)vd = v0; *(f16x8*)(vd + 8) = v1;
    }
}

// ---------------------------------------------------------------------------
// Kernel 3: flash attention.
//   S^T = K·Q^T (per-lane softmax state), O^T = V^T·P^T (P^T via LDS bounce)
//   K/V double-buffered in LDS; 1 barrier/kt; stride-68 b64 DS ops (0 conflicts).
//   1D swizzled grid: id%8 = XCD slot; the 8 qt-siblings of a bh occupy
//   adjacent slots on ONE XCD -> K/V (256KB/bh) served from that XCD's L2.
// Block: 256 thr = 4 waves x 32 qrows.
// ---------------------------------------------------------------------------
__global__ __launch_bounds__(256, 3) void flash_kernel(const f16* __restrict__ Qb,
                                                       const f16* __restrict__ Kb,
                                                       const f16* __restrict__ Vtb,
                                                       f16* __restrict__ attn) {
    __shared__ __align__(16) f16 kv_lds[2][2][64 * KST];   // [buf][K/V][row*KST]
    __shared__ __align__(16) f16 p_lds[4][2][16 * KST];    // [wave][ntile][qrow*KST]

    const int id   = blockIdx.x;
    const int xcd  = id & 7;
    const int kk   = id >> 3;
    const int qt   = kk & 7;
    const int bh   = ((kk >> 3) << 3) | xcd;   // qt-siblings of bh share id%8
    const int b    = bh >> 3, h = bh & 7;
    const int tid  = threadIdx.x;
    const int wave = tid >> 6, lane = tid & 63;
    const int quad = lane >> 4, l16 = lane & 15;

    const f16* kg = Kb  + (size_t)bh * SEQ * HD;
    const f16* vg = Vtb + (size_t)bh * HD * SEQ;
    const int srow = tid >> 2, scol = (tid & 3) * 16;

    // stage kt = 0
    {
        const f16* kp = kg + (size_t)srow * HD + scol;
        const f16* vp = vg + (size_t)srow * SEQ + scol;
        f16x8 k0 = *(const f16x8*)kp, k1 = *(const f16x8*)(kp + 8);
        f16x8 v0 = *(const f16x8*)vp, v1 = *(const f16x8*)(vp + 8);
        st8(&kv_lds[0][0][srow * KST + scol], k0);
        st8(&kv_lds[0][0][srow * KST + scol + 8], k1);
        st8(&kv_lds[0][1][srow * KST + scol], v0);
        st8(&kv_lds[0][1][srow * KST + scol + 8], v1);
    }

    // Q fragments (B-operand): lane holds Q[qrow=l16][d=quad*8+j], pre-scaled
    const f16* Qp = Qb + ((size_t)bh * SEQ + qt * 128 + wave * 32) * HD;
    f16x8 qf[2][2];
    for (int j = 0; j < 2; j++)
        for (int ss = 0; ss < 2; ss++)
            qf[j][ss] = *(const f16x8*)(Qp + (size_t)(j * 16 + l16) * HD + ss * 32 + quad * 8);

    float m_st[2] = {-INFINITY, -INFINITY};
    float l_st[2] = {0.f, 0.f};
    f32x4 o[4][2];
    f32x4 z = {0.f, 0.f, 0.f, 0.f};
    for (int mt = 0; mt < 4; mt++) { o[mt][0] = z; o[mt][1] = z; }

    __syncthreads();

    for (int kt = 0; kt < SEQ / 64; kt++) {
        const int buf = kt & 1;

        // prefetch next K/V tile into registers (consumed after compute)
        f16x8 pk0, pk1, pv0, pv1;
        if (kt < SEQ / 64 - 1) {
            const f16* kn = kg + (size_t)((kt + 1) * 64 + srow) * HD + scol;
            const f16* vn = vg + (size_t)srow * SEQ + (kt + 1) * 64 + scol;
            pk0 = *(const f16x8*)kn; pk1 = *(const f16x8*)(kn + 8);
            pv0 = *(const f16x8*)vn; pv1 = *(const f16x8*)(vn + 8);
        }

        const f16* ks = &kv_lds[buf][0][0];
        const f16* vs = &kv_lds[buf][1][0];

        // ---- S^T = K · Q^T ----
        f32x4 s[4][2];
        for (int ct = 0; ct < 4; ct++) {
            f16x8 ka = ld8(ks + (ct * 16 + l16) * KST + quad * 8);
            f16x8 kc = ld8(ks + (ct * 16 + l16) * KST + quad * 8 + 32);
            s[ct][0] = MFMA16(ka, qf[0][0], z, 0, 0, 0);
            s[ct][0] = MFMA16(kc, qf[0][1], s[ct][0], 0, 0, 0);
            s[ct][1] = MFMA16(ka, qf[1][0], z, 0, 0, 0);
            s[ct][1] = MFMA16(kc, qf[1][1], s[ct][1], 0, 0, 0);
        }

        // ---- online softmax, exp2 domain (per-lane state, col=qrow=l16) ----
        for (int j = 0; j < 2; j++) {
            float mx = fmaxf(fmaxf(fmaxf(s[0][j][0], s[0][j][1]), fmaxf(s[0][j][2], s[0][j][3])),
                             fmaxf(fmaxf(s[1][j][0], s[1][j][1]), fmaxf(s[1][j][2], s[1][j][3])));
            mx = fmaxf(mx, fmaxf(fmaxf(fmaxf(s[2][j][0], s[2][j][1]), fmaxf(s[2][j][2], s[2][j][3])),
                                 fmaxf(fmaxf(s[3][j][0], s[3][j][1]), fmaxf(s[3][j][2], s[3][j][3]))));
            mx = fmaxf(mx, __shfl_xor(mx, 16, 64));
            mx = fmaxf(mx, __shfl_xor(mx, 32, 64));
            float mn = fmaxf(m_st[j], mx);
            float al = EXP2F(m_st[j] - mn);
            m_st[j] = mn;
            float rs = 0.f;
            for (int ct = 0; ct < 4; ct++)
                for (int r = 0; r < 4; r++) {
                    float p = EXP2F(s[ct][j][r] - mn);
                    s[ct][j][r] = p;
                    rs += p;
                }
            rs += __shfl_xor(rs, 16, 64);
            rs += __shfl_xor(rs, 32, 64);
            l_st[j] = l_st[j] * al + rs;
            for (int mt = 0; mt < 4; mt++) o[mt][j] *= al;

            // P^T -> per-wave LDS: packed cvt + single b64 store
            for (int ct = 0; ct < 4; ct++) {
                h16x2 lo = __builtin_amdgcn_cvt_pkrtz(s[ct][j][0], s[ct][j][1]);
                h16x2 hi = __builtin_amdgcn_cvt_pkrtz(s[ct][j][2], s[ct][j][3]);
                uint2 w = {__builtin_bit_cast(unsigned int, lo),
                           __builtin_bit_cast(unsigned int, hi)};
                *(uint2*)(&p_lds[wave][j][l16 * KST + ct * 16 + quad * 4]) = w;
            }
        }

        __asm__ volatile("s_waitcnt lgkmcnt(0)" ::: "memory");

        // ---- O^T += V^T · P^T ----
        {
            f16x8 va[4];
            for (int mt = 0; mt < 4; mt++)
                va[mt] = ld8(vs + (mt * 16 + l16) * KST + quad * 8);
            f16x8 p0 = ld8(&p_lds[wave][0][l16 * KST + quad * 8]);
            f16x8 p1 = ld8(&p_lds[wave][1][l16 * KST + quad * 8]);
            for (int mt = 0; mt < 4; mt++) {
                o[mt][0] = MFMA16(va[mt], p0, o[mt][0], 0, 0, 0);
                o[mt][1] = MFMA16(va[mt], p1, o[mt][1], 0, 0, 0);
            }
            for (int mt = 0; mt < 4; mt++)
                va[mt] = ld8(vs + (mt * 16 + l16) * KST + quad * 8 + 32);
            p0 = ld8(&p_lds[wave][0][l16 * KST + quad * 8 + 32]);
            p1 = ld8(&p_lds[wave][1][l16 * KST + quad * 8 + 32]);
            for (int mt = 0; mt < 4; mt++) {
                o[mt][0] = MFMA16(va[mt], p0, o[mt][0], 0, 0, 0);
                o[mt][1] = MFMA16(va[mt], p1, o[mt][1], 0, 0, 0);
            }
        }

        // write prefetched tile to the other buffer
        if (kt < SEQ / 64 - 1) {
            const int nb = buf ^ 1;
            st8(&kv_lds[nb][0][srow * KST + scol], pk0);
            st8(&kv_lds[nb][0][srow * KST + scol + 8], pk1);
            st8(&kv_lds[nb][1][srow * KST + scol], pv0);
            st8(&kv_lds[nb][1][srow * KST + scol + 8], pv1);
        }
        __syncthreads();
    }

    // epilogue: attn[b][n][h*64+d], post-softmax /8 folded in
    for (int j = 0; j < 2; j++) {
        float sc = 1.0f / (8.0f * l_st[j]);
        int n = qt * 128 + wave * 32 + j * 16 + l16;
        f16* op = attn + ((size_t)b * SEQ + n) * HID + h * HD + quad * 4;
        for (int mt = 0; mt < 4; mt++) {
            f16x4 w = {(f16)(o[mt][j][0] * sc), (f16)(o[mt][j][1] * sc),
                       (f16)(o[mt][j][2] * sc), (f16)(o[mt][j][3] * sc)};
            *(f16x4*)(op + mt * 16) = w;
        }
    }
}

// ---------------------------------------------------------------------------
// Kernel 4: output projection. attn (32768 x 512) @ w_proj (512 x 64) + b.
// ---------------------------------------------------------------------------
__global__ __launch_bounds__(256) void proj_kernel(const f16* __restrict__ attn,
                                                   const f16* __restrict__ wTp,
                                                   const float* __restrict__ b_proj,
                                                   float* __restrict__ out) {
    __shared__ __align__(16) f16 a_lds[64][72];
    __shared__ __align__(16) f16 w_lds[64][72];

    const int blk  = blockIdx.x;
    const int tid  = threadIdx.x;
    const int wave = tid >> 6, lane = tid & 63;
    const int quad = lane >> 4, l16 = lane & 15;

    f32x4 acc[4];
    f32x4 z = {0.f, 0.f, 0.f, 0.f};
    for (int ct = 0; ct < 4; ct++) acc[ct] = z;

    for (int kt = 0; kt < 8; kt++) {
        __syncthreads();
        for (int p = 0; p < 2; p++) {
            int t = tid + p * 256;
            int row = t >> 3, col = (t & 7) * 8;
            *(f16x8*)(&a_lds[row][col]) =
                *(const f16x8*)(attn + ((size_t)(blk * 64 + row)) * HID + kt * 64 + col);
            *(f16x8*)(&w_lds[row][col]) =
                *(const f16x8*)(wTp + (size_t)row * HID + kt * 64 + col);
        }
        __syncthreads();
        for (int ss = 0; ss < 2; ss++) {
            f16x8 af = *(const f16x8*)(&a_lds[wave * 16 + l16][quad * 8 + ss * 32]);
            for (int ct = 0; ct < 4; ct++) {
                f16x8 bf = *(const f16x8*)(&w_lds[ct * 16 + l16][quad * 8 + ss * 32]);
                acc[ct] = MFMA16(af, bf, acc[ct], 0, 0, 0);
            }
        }
    }

    for (int ct = 0; ct < 4; ct++) {
        float bias = b_proj[ct * 16 + l16];
        for (int r = 0; r < 4; r++) {
            int row = blk * 64 + wave * 16 + quad * 4 + r;
            out[(size_t)row * HD + ct * 16 + l16] = acc[ct][r] + bias;
        }
    }
}

// ---------------------------------------------------------------------------
extern "C" void kernel_launch(void* const* d_in, const int* in_sizes, int n_in,
                              void* d_out, int out_size, void* d_ws, size_t ws_size,
                              hipStream_t stream) {
    (void)in_sizes; (void)n_in; (void)out_size; (void)ws_size;
    const float* x      = (const float*)d_in[0];
    const float* w_qkv  = (const float*)d_in[1];
    const float* b_qkv  = (const float*)d_in[2];
    const float* w_proj = (const float*)d_in[3];
    const float* b_proj = (const float*)d_in[4];
    float* out = (float*)d_out;

    char* ws = (char*)d_ws;
    const size_t QKV_EL = (size_t)BATCH * NH * SEQ * HD;
    f16* wTq  = (f16*)(ws);
    f16* wTp  = (f16*)(ws + 196608);
    f16* Qb   = (f16*)(ws + 262144);
    f16* Kb   = (f16*)(ws + 262144 + 2 * QKV_EL);
    f16* Vtb  = (f16*)(ws + 262144 + 4 * QKV_EL);
    f16* attn = (f16*)(ws + 262144 + 6 * QKV_EL);

    transpose_w<<<512, 256, 0, stream>>>(w_qkv, w_proj, wTq, wTp);
    qkv_kernel<<<dim3(16, BATCH * NH), 256, 0, stream>>>(x, wTq, b_qkv, Qb, Kb, Vtb);
    flash_kernel<<<2048, 256, 0, stream>>>(Qb, Kb, Vtb, attn);
    proj_kernel<<<512, 256, 0, stream>>>(attn, wTp, b_proj, out);
}